// Round 2
// baseline (618.141 us; speedup 1.0000x reference)
//
#include <hip/hip_runtime.h>

using u16 = unsigned short;
using u32 = unsigned int;

typedef __bf16 bf16x8 __attribute__((ext_vector_type(8)));
typedef float f32x4 __attribute__((ext_vector_type(4)));

__device__ __forceinline__ float bf2f(u16 v) {
  union { u32 u; float f; } c; c.u = ((u32)v) << 16; return c.f;
}
__device__ __forceinline__ u16 f2bf(float f) {
  union { float f; u32 u; } c; c.f = f;
  u32 u = c.u;
  u32 r = u + 0x7fffu + ((u >> 16) & 1u);   // RNE
  return (u16)(r >> 16);
}
__device__ __forceinline__ u32 pack2(float a, float b) {
  return (u32)f2bf(a) | ((u32)f2bf(b) << 16);
}

constexpr int Bb  = 64;    // graphs
constexpr int L   = 1024;  // nodes/graph
constexpr int K   = 16;    // kNN
constexpr int IN  = 128;
constexpr int OUT = 128;
constexpr int FLR = 64;
constexpr int N   = Bb * L;
constexpr int FEAT = IN + 2 * FLR;  // 256

// ---------------------------------------------------------------------------
// Kernel A: s = x@Ws+bs (fp32), h = x@Wh+bh (fp32->bf16), feats[:,0:128]=bf16(x)
// All inputs fp32. Weight indices are wave-uniform -> scalar loads.
// ---------------------------------------------------------------------------
__global__ __launch_bounds__(256) void k_sh(
    const float* __restrict__ x, const float* __restrict__ Ws, const float* __restrict__ bs,
    const float* __restrict__ Wh, const float* __restrict__ bh,
    float* __restrict__ s_buf, u16* __restrict__ h_buf, u16* __restrict__ feats)
{
  const int node = blockIdx.x * 256 + threadIdx.x;
  const float* xr = x + (size_t)node * IN;
  u16* fr = feats + (size_t)node * FEAT;

  float s0 = bs[0], s1 = bs[1], s2 = bs[2], s3 = bs[3];
  float h[FLR];
#pragma unroll
  for (int o = 0; o < FLR; ++o) h[o] = bh[o];

  for (int f = 0; f < IN; f += 8) {
    float4 xa = *(const float4*)(xr + f);
    float4 xb = *(const float4*)(xr + f + 4);
    float xv[8] = {xa.x, xa.y, xa.z, xa.w, xb.x, xb.y, xb.z, xb.w};
    uint4 p;
    p.x = pack2(xv[0], xv[1]); p.y = pack2(xv[2], xv[3]);
    p.z = pack2(xv[4], xv[5]); p.w = pack2(xv[6], xv[7]);
    *(uint4*)(fr + f) = p;                 // feats x-part (bf16)
#pragma unroll
    for (int t = 0; t < 8; ++t) {
      const int ff = f + t;
      float xvt = xv[t];
      s0 = fmaf(xvt, Ws[ff * 4 + 0], s0);
      s1 = fmaf(xvt, Ws[ff * 4 + 1], s1);
      s2 = fmaf(xvt, Ws[ff * 4 + 2], s2);
      s3 = fmaf(xvt, Ws[ff * 4 + 3], s3);
      const float* wr = Wh + ff * FLR;
#pragma unroll
      for (int o = 0; o < FLR; ++o) h[o] = fmaf(xvt, wr[o], h[o]);
    }
  }
  float4 sv; sv.x = s0; sv.y = s1; sv.z = s2; sv.w = s3;
  *(float4*)(s_buf + (size_t)node * 4) = sv;

  u16* hr = h_buf + (size_t)node * FLR;
#pragma unroll
  for (int o = 0; o < FLR; o += 8) {
    uint4 p;
    p.x = pack2(h[o + 0], h[o + 1]); p.y = pack2(h[o + 2], h[o + 3]);
    p.z = pack2(h[o + 4], h[o + 5]); p.w = pack2(h[o + 6], h[o + 7]);
    *(uint4*)(hr + o) = p;
  }
}

// ---------------------------------------------------------------------------
// Kernel B: per-node top-K (K=16) over its graph's 1024 nodes, then
// w=exp(-10*d2), gather bf16 h, mean/max aggregate -> feats[:,128:256] (bf16).
// Sorted-insertion network fully unrolled (cndmask only). Tie-break: lower j
// first, matching jax.lax.top_k.
// ---------------------------------------------------------------------------
__global__ __launch_bounds__(128) void k_knn(
    const float* __restrict__ s_buf, const u16* __restrict__ h_buf,
    u16* __restrict__ feats)
{
  const int g  = blockIdx.y;
  const int li = blockIdx.x * 128 + threadIdx.x;
  const int node = g * L + li;

  const float4 si = *(const float4*)(s_buf + (size_t)node * 4);
  const float4* __restrict__ sg = (const float4*)(s_buf + (size_t)g * L * 4);

  float bd[K]; int bi[K];
#pragma unroll
  for (int k = 0; k < K; ++k) { bd[k] = 3.0e38f; bi[k] = 0; }

#pragma unroll 2
  for (int j = 0; j < L; ++j) {
    float4 sj = sg[j];
    float dx = si.x - sj.x, dy = si.y - sj.y, dz = si.z - sj.z, dw = si.w - sj.w;
    float d2 = fmaf(dw, dw, fmaf(dz, dz, fmaf(dy, dy, dx * dx)));
    if (d2 < bd[K - 1]) {
      bool ins0 = d2 < bd[0];
#pragma unroll
      for (int k = K - 1; k >= 1; --k) {
        bool shift = d2 < bd[k - 1];
        bool here  = !shift && (d2 < bd[k]);
        bd[k] = shift ? bd[k - 1] : (here ? d2 : bd[k]);
        bi[k] = shift ? bi[k - 1] : (here ? j  : bi[k]);
      }
      if (ins0) { bd[0] = d2; bi[0] = j; }
    }
  }

  float w[K];
#pragma unroll
  for (int k = 0; k < K; ++k) w[k] = __expf(-10.0f * bd[k]);

  const u16* __restrict__ hg = h_buf + (size_t)g * L * FLR;
  u16* fr = feats + (size_t)node * FEAT;

#pragma unroll
  for (int c = 0; c < 4; ++c) {          // 4 chunks of 16 features
    float mean[16], mx[16];
#pragma unroll
    for (int t = 0; t < 16; ++t) { mean[t] = 0.0f; mx[t] = -3.0e38f; }
    for (int k = 0; k < K; ++k) {
      const u16* hr = hg + (size_t)bi[k] * FLR + c * 16;
      uint4 a  = *(const uint4*)(hr);
      uint4 b2 = *(const uint4*)(hr + 8);
      float wk = w[k];
      u32 pw[8] = {a.x, a.y, a.z, a.w, b2.x, b2.y, b2.z, b2.w};
#pragma unroll
      for (int t = 0; t < 16; ++t) {
        float v = bf2f((u16)(pw[t >> 1] >> ((t & 1) * 16))) * wk;
        mean[t] += v;
        mx[t] = fmaxf(mx[t], v);
      }
    }
    u32 pmv[8], pxv[8];
#pragma unroll
    for (int t = 0; t < 16; t += 2) {
      pmv[t >> 1] = pack2(mean[t] * 0.0625f, mean[t + 1] * 0.0625f);  // /K
      pxv[t >> 1] = pack2(mx[t], mx[t + 1]);
    }
    uint4 q0, q1;
    q0.x = pmv[0]; q0.y = pmv[1]; q0.z = pmv[2]; q0.w = pmv[3];
    q1.x = pmv[4]; q1.y = pmv[5]; q1.z = pmv[6]; q1.w = pmv[7];
    *(uint4*)(fr + IN + c * 16)     = q0;
    *(uint4*)(fr + IN + c * 16 + 8) = q1;
    q0.x = pxv[0]; q0.y = pxv[1]; q0.z = pxv[2]; q0.w = pxv[3];
    q1.x = pxv[4]; q1.y = pxv[5]; q1.z = pxv[6]; q1.w = pxv[7];
    *(uint4*)(fr + IN + FLR + c * 16)     = q0;
    *(uint4*)(fr + IN + FLR + c * 16 + 8) = q1;
  }
}

// ---------------------------------------------------------------------------
// Kernel P: repack fp32 W_out[256][128] into bf16 MFMA B-fragment order:
// element j of lane's frag = W[kstep*32+(lane>>4)*8+j][ntile*16+(lane&15)]
// ---------------------------------------------------------------------------
__global__ void k_pack(const float* __restrict__ Wout, u16* __restrict__ Bp)
{
  int t = blockIdx.x * 256 + threadIdx.x;    // 8 ntile * 8 kstep * 64 lane
  if (t >= 8 * 8 * 64) return;
  int lane = t & 63, kstep = (t >> 6) & 7, ntile = t >> 9;
  int n  = ntile * 16 + (lane & 15);
  int kb = kstep * 32 + (lane >> 4) * 8;
  u16* dst = Bp + (size_t)t * 8;
#pragma unroll
  for (int j = 0; j < 8; ++j) dst[j] = f2bf(Wout[(kb + j) * OUT + n]);
}

// ---------------------------------------------------------------------------
// Kernel C: out = relu(feats @ W_out + b_out), MFMA 16x16x32 bf16, fp32 out.
// Per wave: 16 rows x 128 cols, K=256 in 8 steps, acc = 8 tiles x f32x4.
// A-frag: m=lane&15, k=(lane>>4)*8+j.  C/D: col=lane&15, row=(lane>>4)*4+reg.
// ---------------------------------------------------------------------------
__global__ __launch_bounds__(256) void k_out(
    const u16* __restrict__ feats, const u16* __restrict__ Bp,
    const float* __restrict__ bout, float* __restrict__ out)
{
  const int wave = threadIdx.x >> 6;
  const int lane = threadIdx.x & 63;
  const int mbase = blockIdx.x * 64 + wave * 16;
  const int arow = mbase + (lane & 15);
  const int kq = (lane >> 4) * 8;

  f32x4 acc[8];
#pragma unroll
  for (int nt = 0; nt < 8; ++nt) acc[nt] = f32x4{0.f, 0.f, 0.f, 0.f};

  const bf16x8* __restrict__ bp = (const bf16x8*)Bp;
#pragma unroll
  for (int ks = 0; ks < 8; ++ks) {
    bf16x8 a = *(const bf16x8*)(feats + (size_t)arow * FEAT + ks * 32 + kq);
#pragma unroll
    for (int nt = 0; nt < 8; ++nt) {
      bf16x8 b = bp[(nt * 8 + ks) * 64 + lane];
      acc[nt] = __builtin_amdgcn_mfma_f32_16x16x32_bf16(a, b, acc[nt], 0, 0, 0);
    }
  }

  const int rbase = (lane >> 4) * 4;
  const int col = lane & 15;
#pragma unroll
  for (int nt = 0; nt < 8; ++nt) {
    float bias = bout[nt * 16 + col];
#pragma unroll
    for (int r = 0; r < 4; ++r) {
      float v = acc[nt][r] + bias;
      out[(size_t)(mbase + rbase + r) * OUT + nt * 16 + col] = fmaxf(v, 0.0f);
    }
  }
}

extern "C" void kernel_launch(void* const* d_in, const int* in_sizes, int n_in,
                              void* d_out, int out_size, void* d_ws, size_t ws_size,
                              hipStream_t stream) {
  const float* x    = (const float*)d_in[0];
  const float* Ws   = (const float*)d_in[1];
  const float* bs   = (const float*)d_in[2];
  const float* Wh   = (const float*)d_in[3];
  const float* bh   = (const float*)d_in[4];
  const float* Wout = (const float*)d_in[5];
  const float* bout = (const float*)d_in[6];
  float* out = (float*)d_out;

  char* ws = (char*)d_ws;
  float* s_buf = (float*)ws;                                     // 1 MiB
  u16*   h_buf = (u16*)(ws + (1 << 20));                         // 8 MiB
  u16*   Bp    = (u16*)(ws + (1 << 20) + (8 << 20));             // 128 KiB
  u16*   feats = (u16*)(ws + (1 << 20) + (8 << 20) + (1 << 17)); // 32 MiB

  k_sh<<<N / 256, 256, 0, stream>>>(x, Ws, bs, Wh, bh, s_buf, h_buf, feats);
  k_pack<<<16, 256, 0, stream>>>(Wout, Bp);
  dim3 gknn(L / 128, Bb);
  k_knn<<<gknn, 128, 0, stream>>>(s_buf, h_buf, feats);
  k_out<<<N / 64, 256, 0, stream>>>(feats, Bp, bout, out);
}

// Round 3
// 281.374 us; speedup vs baseline: 2.1969x; 2.1969x over previous
//
#include <hip/hip_runtime.h>

using u16 = unsigned short;
using u32 = unsigned int;

typedef __bf16 bf16x8 __attribute__((ext_vector_type(8)));
typedef float f32x4 __attribute__((ext_vector_type(4)));

__device__ __forceinline__ u16 f2bf(float f) {
  union { float f; u32 u; } c; c.f = f;
  u32 u = c.u;
  u32 r = u + 0x7fffu + ((u >> 16) & 1u);   // RNE
  return (u16)(r >> 16);
}
__device__ __forceinline__ u32 pack2(float a, float b) {
  return (u32)f2bf(a) | ((u32)f2bf(b) << 16);
}

constexpr int Bb  = 64;    // graphs
constexpr int L   = 1024;  // nodes/graph
constexpr int IN  = 128;
constexpr int OUT = 128;
constexpr int FLR = 64;
constexpr int N   = Bb * L;
constexpr int FEAT = IN + 2 * FLR;  // 256

// ---------------------------------------------------------------------------
// k_sh: block=256 (4 waves) covers 64 nodes. Wave w computes h columns
// [w*16, w*16+16) over all 128 inputs (weight addresses wave-uniform via
// readfirstlane -> s_load), writes its bf16 h slice and its bf16 x-copy
// slice of feats. Wave 0 additionally computes s (fp32). Grid = 1024 blocks
// -> 4096 waves = 4/SIMD (vs 1/SIMD before).
// ---------------------------------------------------------------------------
__global__ __launch_bounds__(256) void k_sh(
    const float* __restrict__ x, const float* __restrict__ Ws, const float* __restrict__ bs,
    const float* __restrict__ Wh, const float* __restrict__ bh,
    float* __restrict__ s_buf, u16* __restrict__ h_buf, u16* __restrict__ feats)
{
  const int lane = threadIdx.x & 63;
  const int wq = __builtin_amdgcn_readfirstlane(threadIdx.x >> 6);
  const int node = blockIdx.x * 64 + lane;
  const float* xr = x + (size_t)node * IN;
  const int ob = wq * 16;

  float h[16];
#pragma unroll
  for (int o = 0; o < 16; ++o) h[o] = bh[ob + o];

  for (int f = 0; f < IN; f += 4) {
    float4 xc = *(const float4*)(xr + f);
    float xv[4] = {xc.x, xc.y, xc.z, xc.w};
#pragma unroll
    for (int t = 0; t < 4; ++t) {
      const float* wr = Wh + (size_t)(f + t) * FLR + ob;
#pragma unroll
      for (int o = 0; o < 16; ++o) h[o] = fmaf(xv[t], wr[o], h[o]);
    }
  }

  u16* hr = h_buf + (size_t)node * FLR + ob;
  uint4 p;
  p.x = pack2(h[0], h[1]);  p.y = pack2(h[2], h[3]);
  p.z = pack2(h[4], h[5]);  p.w = pack2(h[6], h[7]);
  *(uint4*)(hr) = p;
  p.x = pack2(h[8], h[9]);  p.y = pack2(h[10], h[11]);
  p.z = pack2(h[12], h[13]); p.w = pack2(h[14], h[15]);
  *(uint4*)(hr + 8) = p;

  // feats x-copy: wave w writes cols [w*32, w*32+32)
  {
    const float* xc0 = xr + wq * 32;
    u16* fc = feats + (size_t)node * FEAT + wq * 32;
#pragma unroll
    for (int i = 0; i < 32; i += 8) {
      float4 a  = *(const float4*)(xc0 + i);
      float4 b2 = *(const float4*)(xc0 + i + 4);
      uint4 q;
      q.x = pack2(a.x, a.y);  q.y = pack2(a.z, a.w);
      q.z = pack2(b2.x, b2.y); q.w = pack2(b2.z, b2.w);
      *(uint4*)(fc + i) = q;
    }
  }

  if (wq == 0) {
    float s0 = bs[0], s1 = bs[1], s2 = bs[2], s3 = bs[3];
    for (int f = 0; f < IN; f += 4) {
      float4 xc = *(const float4*)(xr + f);
      float xv[4] = {xc.x, xc.y, xc.z, xc.w};
#pragma unroll
      for (int t = 0; t < 4; ++t) {
        const float* wr = Ws + (size_t)(f + t) * 4;
        s0 = fmaf(xv[t], wr[0], s0);
        s1 = fmaf(xv[t], wr[1], s1);
        s2 = fmaf(xv[t], wr[2], s2);
        s3 = fmaf(xv[t], wr[3], s3);
      }
    }
    float4 sv; sv.x = s0; sv.y = s1; sv.z = s2; sv.w = s3;
    *(float4*)(s_buf + (size_t)node * 4) = sv;
  }
}

// ---------------------------------------------------------------------------
// k_knn: block=128 (2 waves) covers 64 nodes of one graph. Wave w scans
// candidates [w*512, w*512+512) with wave-uniform s addresses (s_load).
// Selection key = (bits(d2) & ~1023) | j : positive-float order == uint
// order, ties break to lower j (matches lax.top_k). Branch-free sorted
// top-16 via v_med3_f32 chain (16 ops/candidate). Halves merged with the
// bitonic min(A[i],B[15-i]) identity through LDS; each wave aggregates 8
// of the 16 neighbors; wave 0 combines + writes feats[:,128:256] bf16.
// ---------------------------------------------------------------------------
__global__ __launch_bounds__(128) void k_knn(
    const float* __restrict__ s_buf, const u16* __restrict__ h_buf,
    u16* __restrict__ feats)
{
  __shared__ float lds[64 * 129];   // 33 KB; reused: keys phase then partials
  const int lane = threadIdx.x & 63;
  const int w = __builtin_amdgcn_readfirstlane(threadIdx.x >> 6);
  const int g = blockIdx.y;
  const int li = blockIdx.x * 64 + lane;     // node index within graph
  const int node = g * L + li;

  const float4 si = *(const float4*)(s_buf + (size_t)node * 4);
  const float4* __restrict__ sg = (const float4*)(s_buf + (size_t)g * L * 4);
  const int jb = __builtin_amdgcn_readfirstlane(w * 512);

  float b[16];
#pragma unroll
  for (int k = 0; k < 16; ++k) b[k] = 3.0e38f;

#pragma unroll 4
  for (int j = 0; j < 512; ++j) {
    float4 sj = sg[jb + j];
    float dx = si.x - sj.x, dy = si.y - sj.y;
    float dz = si.z - sj.z, dw2 = si.w - sj.w;
    float d2 = fmaf(dw2, dw2, fmaf(dz, dz, fmaf(dy, dy, dx * dx)));
    u32 db = __float_as_uint(d2);
    float key = __uint_as_float((db & 0xFFFFFC00u) | (u32)(jb + j));
#pragma unroll
    for (int k = 15; k >= 1; --k) b[k] = __builtin_amdgcn_fmed3f(key, b[k - 1], b[k]);
    b[0] = fminf(key, b[0]);
  }

  // exchange sorted lists (stride 17 dwords -> conflict-free)
#pragma unroll
  for (int k = 0; k < 16; ++k) lds[(w * 64 + lane) * 17 + k] = b[k];
  __syncthreads();
  float mk[8];   // my 8 of the merged top-16: min(A[i], B[15-i])
#pragma unroll
  for (int i = 0; i < 8; ++i)
    mk[i] = fminf(b[i], lds[((1 - w) * 64 + lane) * 17 + (15 - i)]);
  __syncthreads();   // keys reads done; LDS reused for partials

  float mean[64], mx[64];
#pragma unroll
  for (int c = 0; c < 64; ++c) { mean[c] = 0.0f; mx[c] = -3.0e38f; }

  const u16* __restrict__ hg = h_buf + (size_t)g * L * FLR;
#pragma unroll
  for (int i = 0; i < 8; ++i) {
    u32 kb2 = __float_as_uint(mk[i]);
    int idx = (int)(kb2 & 1023u);
    float d2t = __uint_as_float(kb2 & 0xFFFFFC00u);
    float wk = __expf(-10.0f * d2t);
    const uint4* hr = (const uint4*)(hg + (size_t)idx * FLR);
#pragma unroll
    for (int q = 0; q < 8; ++q) {
      uint4 pw = hr[q];
      u32 pp[4] = {pw.x, pw.y, pw.z, pw.w};
#pragma unroll
      for (int t2 = 0; t2 < 4; ++t2) {
        int o = q * 8 + t2 * 2;
        float v0 = __uint_as_float(pp[t2] << 16) * wk;
        float v1 = __uint_as_float(pp[t2] & 0xFFFF0000u) * wk;
        mean[o]     += v0;  mx[o]     = fmaxf(mx[o], v0);
        mean[o + 1] += v1;  mx[o + 1] = fmaxf(mx[o + 1], v1);
      }
    }
  }

  if (w == 1) {
#pragma unroll
    for (int c = 0; c < 64; ++c) lds[lane * 129 + c] = mean[c];
#pragma unroll
    for (int c = 0; c < 64; ++c) lds[lane * 129 + 64 + c] = mx[c];
  }
  __syncthreads();
  if (w == 0) {
    u16* fr = feats + (size_t)node * FEAT + IN;
#pragma unroll
    for (int c = 0; c < 64; c += 8) {
      float m[8];
#pragma unroll
      for (int t = 0; t < 8; ++t)
        m[t] = (mean[c + t] + lds[lane * 129 + c + t]) * 0.0625f;
      uint4 q;
      q.x = pack2(m[0], m[1]); q.y = pack2(m[2], m[3]);
      q.z = pack2(m[4], m[5]); q.w = pack2(m[6], m[7]);
      *(uint4*)(fr + c) = q;
    }
#pragma unroll
    for (int c = 0; c < 64; c += 8) {
      float m[8];
#pragma unroll
      for (int t = 0; t < 8; ++t)
        m[t] = fmaxf(mx[c + t], lds[lane * 129 + 64 + c + t]);
      uint4 q;
      q.x = pack2(m[0], m[1]); q.y = pack2(m[2], m[3]);
      q.z = pack2(m[4], m[5]); q.w = pack2(m[6], m[7]);
      *(uint4*)(fr + 64 + c) = q;
    }
  }
}

// ---------------------------------------------------------------------------
// k_pack: repack fp32 W_out[256][128] into bf16 MFMA B-fragment order.
// ---------------------------------------------------------------------------
__global__ void k_pack(const float* __restrict__ Wout, u16* __restrict__ Bp)
{
  int t = blockIdx.x * 256 + threadIdx.x;    // 8 ntile * 8 kstep * 64 lane
  if (t >= 8 * 8 * 64) return;
  int lane = t & 63, kstep = (t >> 6) & 7, ntile = t >> 9;
  int n  = ntile * 16 + (lane & 15);
  int kb = kstep * 32 + (lane >> 4) * 8;
  u16* dst = Bp + (size_t)t * 8;
#pragma unroll
  for (int j = 0; j < 8; ++j) dst[j] = f2bf(Wout[(kb + j) * OUT + n]);
}

// ---------------------------------------------------------------------------
// k_out: out = relu(feats @ W_out + b_out), MFMA 16x16x32 bf16, fp32 out.
// A-frag: m=lane&15, k=(lane>>4)*8+j.  C/D: col=lane&15, row=(lane>>4)*4+reg.
// ---------------------------------------------------------------------------
__global__ __launch_bounds__(256) void k_out(
    const u16* __restrict__ feats, const u16* __restrict__ Bp,
    const float* __restrict__ bout, float* __restrict__ out)
{
  const int wave = threadIdx.x >> 6;
  const int lane = threadIdx.x & 63;
  const int mbase = blockIdx.x * 64 + wave * 16;
  const int arow = mbase + (lane & 15);
  const int kq = (lane >> 4) * 8;

  f32x4 acc[8];
#pragma unroll
  for (int nt = 0; nt < 8; ++nt) acc[nt] = f32x4{0.f, 0.f, 0.f, 0.f};

  const bf16x8* __restrict__ bp = (const bf16x8*)Bp;
#pragma unroll
  for (int ks = 0; ks < 8; ++ks) {
    bf16x8 a = *(const bf16x8*)(feats + (size_t)arow * FEAT + ks * 32 + kq);
#pragma unroll
    for (int nt = 0; nt < 8; ++nt) {
      bf16x8 b = bp[(nt * 8 + ks) * 64 + lane];
      acc[nt] = __builtin_amdgcn_mfma_f32_16x16x32_bf16(a, b, acc[nt], 0, 0, 0);
    }
  }

  const int rbase = (lane >> 4) * 4;
  const int col = lane & 15;
#pragma unroll
  for (int nt = 0; nt < 8; ++nt) {
    float bias = bout[nt * 16 + col];
#pragma unroll
    for (int r = 0; r < 4; ++r) {
      float v = acc[nt][r] + bias;
      out[(size_t)(mbase + rbase + r) * OUT + nt * 16 + col] = fmaxf(v, 0.0f);
    }
  }
}

extern "C" void kernel_launch(void* const* d_in, const int* in_sizes, int n_in,
                              void* d_out, int out_size, void* d_ws, size_t ws_size,
                              hipStream_t stream) {
  const float* x    = (const float*)d_in[0];
  const float* Ws   = (const float*)d_in[1];
  const float* bs   = (const float*)d_in[2];
  const float* Wh   = (const float*)d_in[3];
  const float* bh   = (const float*)d_in[4];
  const float* Wout = (const float*)d_in[5];
  const float* bout = (const float*)d_in[6];
  float* out = (float*)d_out;

  char* ws = (char*)d_ws;
  float* s_buf = (float*)ws;                                     // 1 MiB
  u16*   h_buf = (u16*)(ws + (1 << 20));                         // 8 MiB
  u16*   Bp    = (u16*)(ws + (1 << 20) + (8 << 20));             // 128 KiB
  u16*   feats = (u16*)(ws + (1 << 20) + (8 << 20) + (1 << 17)); // 32 MiB

  k_sh<<<N / 64, 256, 0, stream>>>(x, Ws, bs, Wh, bh, s_buf, h_buf, feats);
  k_pack<<<16, 256, 0, stream>>>(Wout, Bp);
  dim3 gknn(L / 64, Bb);
  k_knn<<<gknn, 128, 0, stream>>>(s_buf, h_buf, feats);
  k_out<<<N / 64, 256, 0, stream>>>(feats, Bp, bout, out);
}

// Round 4
// 204.973 us; speedup vs baseline: 3.0157x; 1.3727x over previous
//
#include <hip/hip_runtime.h>

using u16 = unsigned short;
using u32 = unsigned int;

typedef __bf16 bf16x8 __attribute__((ext_vector_type(8)));
typedef float f32x4 __attribute__((ext_vector_type(4)));

__device__ __forceinline__ u16 f2bf(float f) {
  union { float f; u32 u; } c; c.f = f;
  u32 u = c.u;
  u32 r = u + 0x7fffu + ((u >> 16) & 1u);   // RNE
  return (u16)(r >> 16);
}
__device__ __forceinline__ u32 pack2(float a, float b) {
  return (u32)f2bf(a) | ((u32)f2bf(b) << 16);
}

constexpr int Bb  = 64;    // graphs
constexpr int L   = 1024;  // nodes/graph
constexpr int IN  = 128;
constexpr int OUT = 128;
constexpr int FLR = 64;
constexpr int N   = Bb * L;
constexpr int FEAT = IN + 2 * FLR;  // 256

// ---------------------------------------------------------------------------
// k_sh: block=256 threads / 64 nodes. Phase 1: cooperative coalesced load of
// the 64x128 fp32 x tile into LDS (stride 132: conflict-free AND 16B-aligned),
// plus bf16 x-copy into feats. Phase 2: wave w computes h cols [w*16,w*16+16)
// (weights wave-uniform -> s_load) and s column w (fp32 exact).
// ---------------------------------------------------------------------------
__global__ __launch_bounds__(256) void k_sh(
    const float* __restrict__ x, const float* __restrict__ Ws, const float* __restrict__ bs,
    const float* __restrict__ Wh, const float* __restrict__ bh,
    float* __restrict__ s_buf, u16* __restrict__ h_buf, u16* __restrict__ feats)
{
  __shared__ float xs[64 * 132];
  const int t = threadIdx.x;
  const int blk = blockIdx.x;
  const float* xb = x + (size_t)blk * 64 * IN;

#pragma unroll
  for (int i = 0; i < 8; ++i) {
    int flat = i * 1024 + t * 4;
    float4 v = *(const float4*)(xb + flat);
    int node = flat >> 7, feat = flat & 127;
    *(float4*)(&xs[node * 132 + feat]) = v;
    uint2 pp;
    pp.x = pack2(v.x, v.y); pp.y = pack2(v.z, v.w);
    *(uint2*)(feats + (size_t)(blk * 64 + node) * FEAT + feat) = pp;
  }
  __syncthreads();

  const int lane = t & 63;
  const int w = __builtin_amdgcn_readfirstlane(t >> 6);
  const int node = blk * 64 + lane;
  const int ob = w * 16;

  float h[16];
#pragma unroll
  for (int o = 0; o < 16; ++o) h[o] = bh[ob + o];
  float sacc = bs[w];

  for (int f = 0; f < IN; f += 4) {
    float4 xc = *(const float4*)(&xs[lane * 132 + f]);
    float xv[4] = {xc.x, xc.y, xc.z, xc.w};
#pragma unroll
    for (int tt = 0; tt < 4; ++tt) {
      const float* wr = Wh + (size_t)(f + tt) * FLR + ob;
#pragma unroll
      for (int o = 0; o < 16; ++o) h[o] = fmaf(xv[tt], wr[o], h[o]);
      sacc = fmaf(xv[tt], Ws[(f + tt) * 4 + w], sacc);
    }
  }

  u16* hr = h_buf + (size_t)node * FLR + ob;
  uint4 p;
  p.x = pack2(h[0], h[1]);  p.y = pack2(h[2], h[3]);
  p.z = pack2(h[4], h[5]);  p.w = pack2(h[6], h[7]);
  *(uint4*)(hr) = p;
  p.x = pack2(h[8], h[9]);  p.y = pack2(h[10], h[11]);
  p.z = pack2(h[12], h[13]); p.w = pack2(h[14], h[15]);
  *(uint4*)(hr + 8) = p;

  s_buf[(size_t)node * 4 + w] = sacc;
}

// ---------------------------------------------------------------------------
// k_knn: block=256 (4 waves) covers 64 nodes of one graph (node = lane).
// Wave w scans candidates [w*256,(w+1)*256) with the med3 sorted-insert chain
// on keys = (bits(d2)&~1023)|j  (float order == uint order for d2>=0; ties
// to lower j, matching lax.top_k). Merge 4 sorted lists: bitonic min-identity
// + one in-register bitonic sort-16, then final min-identity (order-free).
// Aggregation is wave-cooperative: lane=(nb 0..7, q 0..7); one uint4 load
// covers 8 neighbor rows x 8 quads (16 lines/instr vs 64 for row-per-lane);
// mean/max reduced over nb via 3 shfl_xor butterfly steps.
// ---------------------------------------------------------------------------
__global__ __launch_bounds__(256) void k_knn(
    const float* __restrict__ s_buf, const u16* __restrict__ h_buf,
    u16* __restrict__ feats)
{
  __shared__ float lists[4 * 64 * 17];   // 17.4 KB, stride 17 = conflict-free
  __shared__ float fk[64 * 17];          // final 16 keys per node (stride 17)

  const int lane = threadIdx.x & 63;
  const int w = __builtin_amdgcn_readfirstlane(threadIdx.x >> 6);
  const int g = blockIdx.y;
  const int nb0 = blockIdx.x * 64;           // first node of this block
  const int node = g * L + nb0 + lane;

  const float4 si = *(const float4*)(s_buf + (size_t)node * 4);
  const float4* __restrict__ sg = (const float4*)(s_buf + (size_t)g * L * 4);
  const int jb = __builtin_amdgcn_readfirstlane(w * 256);

  float b[16];
#pragma unroll
  for (int k = 0; k < 16; ++k) b[k] = 3.0e38f;

#pragma unroll 4
  for (int j = 0; j < 256; ++j) {
    float4 sj = sg[jb + j];
    float dx = si.x - sj.x, dy = si.y - sj.y;
    float dz = si.z - sj.z, dw2 = si.w - sj.w;
    float d2 = fmaf(dw2, dw2, fmaf(dz, dz, fmaf(dy, dy, dx * dx)));
    u32 db = __float_as_uint(d2);
    float key = __uint_as_float((db & 0xFFFFFC00u) | (u32)(jb + j));
#pragma unroll
    for (int k = 15; k >= 1; --k) b[k] = __builtin_amdgcn_fmed3f(key, b[k - 1], b[k]);
    b[0] = fminf(key, b[0]);
  }

  // publish all 4 sorted lists
#pragma unroll
  for (int k = 0; k < 16; ++k) lists[(w * 64 + lane) * 17 + k] = b[k];
  __syncthreads();

  // waves 0,1 merge (own, own+2): min-identity -> bitonic -> sort ascending
  float c[16];
  if (w < 2) {
#pragma unroll
    for (int i = 0; i < 16; ++i) {
      float o = lists[((w + 2) * 64 + lane) * 17 + (15 - i)];
      c[i] = fminf(b[i], o);
    }
#pragma unroll
    for (int d = 8; d >= 1; d >>= 1) {
#pragma unroll
      for (int i = 0; i < 16; ++i) {
        if ((i & d) == 0) {
          float lo = fminf(c[i], c[i | d]);
          float hi = fmaxf(c[i], c[i | d]);
          c[i] = lo; c[i | d] = hi;
        }
      }
    }
  }
  __syncthreads();
  if (w == 0) {
#pragma unroll
    for (int k = 0; k < 16; ++k) lists[lane * 17 + k] = c[k];
  }
  __syncthreads();
  if (w == 1) {
#pragma unroll
    for (int i = 0; i < 16; ++i) {
      float o = lists[lane * 17 + (15 - i)];
      fk[lane * 17 + i] = fminf(c[i], o);   // top-16 of union (unsorted: fine)
    }
  }
  __syncthreads();

  // wave-cooperative aggregation: wave w handles block-local nodes w*16..+15
  const int q  = lane & 7;    // feature quad (8 bf16 = 1 uint4)
  const int nb = lane >> 3;   // neighbor slot (0..7; also slot+8)
  const u16* __restrict__ hg = h_buf + (size_t)g * L * FLR;

#pragma unroll 2
  for (int tt = 0; tt < 16; ++tt) {
    const int nodeL = w * 16 + tt;
    float k1 = fk[nodeL * 17 + nb];
    float k2 = fk[nodeL * 17 + 8 + nb];
    u32 u1 = __float_as_uint(k1), u2 = __float_as_uint(k2);
    float w1 = __expf(-10.0f * __uint_as_float(u1 & 0xFFFFFC00u));
    float w2 = __expf(-10.0f * __uint_as_float(u2 & 0xFFFFFC00u));
    const uint4 a  = ((const uint4*)(hg + (size_t)(u1 & 1023u) * FLR))[q];
    const uint4 b4 = ((const uint4*)(hg + (size_t)(u2 & 1023u) * FLR))[q];
    u32 pa[4] = {a.x, a.y, a.z, a.w};
    u32 pb[4] = {b4.x, b4.y, b4.z, b4.w};
    float m[8], xx[8];
#pragma unroll
    for (int d = 0; d < 4; ++d) {
      float a0 = __uint_as_float(pa[d] << 16) * w1;
      float a1 = __uint_as_float(pa[d] & 0xFFFF0000u) * w1;
      float b0 = __uint_as_float(pb[d] << 16) * w2;
      float b1 = __uint_as_float(pb[d] & 0xFFFF0000u) * w2;
      m[2 * d]     = a0 + b0;  xx[2 * d]     = fmaxf(a0, b0);
      m[2 * d + 1] = a1 + b1;  xx[2 * d + 1] = fmaxf(a1, b1);
    }
#pragma unroll
    for (int mask = 8; mask <= 32; mask <<= 1) {
#pragma unroll
      for (int jj = 0; jj < 8; ++jj) m[jj] += __shfl_xor(m[jj], mask, 64);
#pragma unroll
      for (int jj = 0; jj < 8; ++jj) xx[jj] = fmaxf(xx[jj], __shfl_xor(xx[jj], mask, 64));
    }
    u16* fr = feats + (size_t)(g * L + nb0 + nodeL) * FEAT + IN;
    if (nb == 0) {
      uint4 o;
      o.x = pack2(m[0] * 0.0625f, m[1] * 0.0625f);
      o.y = pack2(m[2] * 0.0625f, m[3] * 0.0625f);
      o.z = pack2(m[4] * 0.0625f, m[5] * 0.0625f);
      o.w = pack2(m[6] * 0.0625f, m[7] * 0.0625f);
      *(uint4*)(fr + q * 8) = o;
    } else if (nb == 1) {
      uint4 o;
      o.x = pack2(xx[0], xx[1]); o.y = pack2(xx[2], xx[3]);
      o.z = pack2(xx[4], xx[5]); o.w = pack2(xx[6], xx[7]);
      *(uint4*)(fr + FLR + q * 8) = o;
    }
  }
}

// ---------------------------------------------------------------------------
// k_pack: repack fp32 W_out[256][128] into bf16 MFMA B-fragment order.
// ---------------------------------------------------------------------------
__global__ void k_pack(const float* __restrict__ Wout, u16* __restrict__ Bp)
{
  int t = blockIdx.x * 256 + threadIdx.x;    // 8 ntile * 8 kstep * 64 lane
  if (t >= 8 * 8 * 64) return;
  int lane = t & 63, kstep = (t >> 6) & 7, ntile = t >> 9;
  int n  = ntile * 16 + (lane & 15);
  int kb = kstep * 32 + (lane >> 4) * 8;
  u16* dst = Bp + (size_t)t * 8;
#pragma unroll
  for (int j = 0; j < 8; ++j) dst[j] = f2bf(Wout[(kb + j) * OUT + n]);
}

// ---------------------------------------------------------------------------
// k_out: out = relu(feats @ W_out + b_out), MFMA 16x16x32 bf16, fp32 out.
// A-frag: m=lane&15, k=(lane>>4)*8+j.  C/D: col=lane&15, row=(lane>>4)*4+reg.
// ---------------------------------------------------------------------------
__global__ __launch_bounds__(256) void k_out(
    const u16* __restrict__ feats, const u16* __restrict__ Bp,
    const float* __restrict__ bout, float* __restrict__ out)
{
  const int wave = threadIdx.x >> 6;
  const int lane = threadIdx.x & 63;
  const int mbase = blockIdx.x * 64 + wave * 16;
  const int arow = mbase + (lane & 15);
  const int kq = (lane >> 4) * 8;

  f32x4 acc[8];
#pragma unroll
  for (int nt = 0; nt < 8; ++nt) acc[nt] = f32x4{0.f, 0.f, 0.f, 0.f};

  const bf16x8* __restrict__ bp = (const bf16x8*)Bp;
#pragma unroll
  for (int ks = 0; ks < 8; ++ks) {
    bf16x8 a = *(const bf16x8*)(feats + (size_t)arow * FEAT + ks * 32 + kq);
#pragma unroll
    for (int nt = 0; nt < 8; ++nt) {
      bf16x8 b = bp[(nt * 8 + ks) * 64 + lane];
      acc[nt] = __builtin_amdgcn_mfma_f32_16x16x32_bf16(a, b, acc[nt], 0, 0, 0);
    }
  }

  const int rbase = (lane >> 4) * 4;
  const int col = lane & 15;
#pragma unroll
  for (int nt = 0; nt < 8; ++nt) {
    float bias = bout[nt * 16 + col];
#pragma unroll
    for (int r = 0; r < 4; ++r) {
      float v = acc[nt][r] + bias;
      out[(size_t)(mbase + rbase + r) * OUT + nt * 16 + col] = fmaxf(v, 0.0f);
    }
  }
}

extern "C" void kernel_launch(void* const* d_in, const int* in_sizes, int n_in,
                              void* d_out, int out_size, void* d_ws, size_t ws_size,
                              hipStream_t stream) {
  const float* x    = (const float*)d_in[0];
  const float* Ws   = (const float*)d_in[1];
  const float* bs   = (const float*)d_in[2];
  const float* Wh   = (const float*)d_in[3];
  const float* bh   = (const float*)d_in[4];
  const float* Wout = (const float*)d_in[5];
  const float* bout = (const float*)d_in[6];
  float* out = (float*)d_out;

  char* ws = (char*)d_ws;
  float* s_buf = (float*)ws;                                     // 1 MiB
  u16*   h_buf = (u16*)(ws + (1 << 20));                         // 8 MiB
  u16*   Bp    = (u16*)(ws + (1 << 20) + (8 << 20));             // 128 KiB
  u16*   feats = (u16*)(ws + (1 << 20) + (8 << 20) + (1 << 17)); // 32 MiB

  k_sh<<<N / 64, 256, 0, stream>>>(x, Ws, bs, Wh, bh, s_buf, h_buf, feats);
  k_pack<<<16, 256, 0, stream>>>(Wout, Bp);
  dim3 gknn(L / 64, Bb);
  k_knn<<<gknn, 256, 0, stream>>>(s_buf, h_buf, feats);
  k_out<<<N / 64, 256, 0, stream>>>(feats, Bp, bout, out);
}

// Round 5
// 198.934 us; speedup vs baseline: 3.1073x; 1.0304x over previous
//
#include <hip/hip_runtime.h>
#include <hip/hip_bf16.h>

using u16 = unsigned short;
using u32 = unsigned int;

typedef __bf16 bf16x8 __attribute__((ext_vector_type(8)));
typedef float f32x4 __attribute__((ext_vector_type(4)));

__device__ __forceinline__ u16 f2bf(float f) {
  union { float f; u32 u; } c; c.f = f;
  u32 u = c.u;
  u32 r = u + 0x7fffu + ((u >> 16) & 1u);   // RNE
  return (u16)(r >> 16);
}
__device__ __forceinline__ u32 pack2(float a, float b) {
  return (u32)f2bf(a) | ((u32)f2bf(b) << 16);
}

constexpr int Bb  = 64;    // graphs
constexpr int L   = 1024;  // nodes/graph
constexpr int IN  = 128;
constexpr int OUT = 128;
constexpr int FLR = 64;
constexpr int N   = Bb * L;

// ---------------------------------------------------------------------------
// k_sh: block=256 threads / 64 nodes. Phase 1: coalesced load of the 64x128
// fp32 x tile into LDS. Phase 2: wave w computes h cols [w*16,w*16+16)
// (weights wave-uniform -> s_load) and s column w (fp32 exact).
// No feats x-copy anymore (k_out converts x in-register).
// ---------------------------------------------------------------------------
__global__ __launch_bounds__(256) void k_sh(
    const float* __restrict__ x, const float* __restrict__ Ws, const float* __restrict__ bs,
    const float* __restrict__ Wh, const float* __restrict__ bh,
    float* __restrict__ s_buf, u16* __restrict__ h_buf)
{
  __shared__ float xs[64 * 132];
  const int t = threadIdx.x;
  const int blk = blockIdx.x;
  const float* xb = x + (size_t)blk * 64 * IN;

#pragma unroll
  for (int i = 0; i < 8; ++i) {
    int flat = i * 1024 + t * 4;
    float4 v = *(const float4*)(xb + flat);
    int node = flat >> 7, feat = flat & 127;
    *(float4*)(&xs[node * 132 + feat]) = v;
  }
  __syncthreads();

  const int lane = t & 63;
  const int w = __builtin_amdgcn_readfirstlane(t >> 6);
  const int node = blk * 64 + lane;
  const int ob = w * 16;

  float h[16];
#pragma unroll
  for (int o = 0; o < 16; ++o) h[o] = bh[ob + o];
  float sacc = bs[w];

  for (int f = 0; f < IN; f += 4) {
    float4 xc = *(const float4*)(&xs[lane * 132 + f]);
    float xv[4] = {xc.x, xc.y, xc.z, xc.w};
#pragma unroll
    for (int tt = 0; tt < 4; ++tt) {
      const float* wr = Wh + (size_t)(f + tt) * FLR + ob;
#pragma unroll
      for (int o = 0; o < 16; ++o) h[o] = fmaf(xv[tt], wr[o], h[o]);
      sacc = fmaf(xv[tt], Ws[(f + tt) * 4 + w], sacc);
    }
  }

  u16* hr = h_buf + (size_t)node * FLR + ob;
  uint4 p;
  p.x = pack2(h[0], h[1]);  p.y = pack2(h[2], h[3]);
  p.z = pack2(h[4], h[5]);  p.w = pack2(h[6], h[7]);
  *(uint4*)(hr) = p;
  p.x = pack2(h[8], h[9]);  p.y = pack2(h[10], h[11]);
  p.z = pack2(h[12], h[13]); p.w = pack2(h[14], h[15]);
  *(uint4*)(hr + 8) = p;

  s_buf[(size_t)node * 4 + w] = sacc;
}

// ---------------------------------------------------------------------------
// k_knn: block=512 (8 waves) covers 64 nodes of one graph (node = lane).
// Wave w scans candidates [w*128,(w+1)*128) with the med3 sorted-insert chain
// on keys = (bits(d2)&~1023)|j (ties -> lower j, matches lax.top_k).
// Merge 8 sorted lists via 3-level tree (bitonic min-identity + 4-layer
// clean; final level set-only). Wave-cooperative aggregation: lane=(nb,q),
// one uint4 load covers 8 neighbor rows x 8 quads; mean/max reduced over nb
// via 3 shfl_xor steps. Output: agg[node][128] bf16 (mean | max).
// ---------------------------------------------------------------------------
__global__ __launch_bounds__(512) void k_knn(
    const float* __restrict__ s_buf, const u16* __restrict__ h_buf,
    u16* __restrict__ agg)
{
  __shared__ float lists[8 * 64 * 17];   // 34.8 KB, stride 17 conflict-free
  __shared__ float fk[64 * 17];          // final 16 keys per node

  const int lane = threadIdx.x & 63;
  const int w = __builtin_amdgcn_readfirstlane(threadIdx.x >> 6);
  const int g = blockIdx.y;
  const int nb0 = blockIdx.x * 64;
  const int node = g * L + nb0 + lane;

  const float4 si = *(const float4*)(s_buf + (size_t)node * 4);
  const float4* __restrict__ sg = (const float4*)(s_buf + (size_t)g * L * 4);
  const int jb = __builtin_amdgcn_readfirstlane(w * 128);

  float b[16];
#pragma unroll
  for (int k = 0; k < 16; ++k) b[k] = 3.0e38f;

#pragma unroll 4
  for (int j = 0; j < 128; ++j) {
    float4 sj = sg[jb + j];
    float dx = si.x - sj.x, dy = si.y - sj.y;
    float dz = si.z - sj.z, dw2 = si.w - sj.w;
    float d2 = fmaf(dw2, dw2, fmaf(dz, dz, fmaf(dy, dy, dx * dx)));
    u32 db = __float_as_uint(d2);
    float key = __uint_as_float((db & 0xFFFFFC00u) | (u32)(jb + j));
#pragma unroll
    for (int k = 15; k >= 1; --k) b[k] = __builtin_amdgcn_fmed3f(key, b[k - 1], b[k]);
    b[0] = fminf(key, b[0]);
  }

#pragma unroll
  for (int k = 0; k < 16; ++k) lists[(w * 64 + lane) * 17 + k] = b[k];
  __syncthreads();

  float c[16];
  // level 1: w<4 merges (w, w+4) -> sorted c -> lists[w]
  if (w < 4) {
#pragma unroll
    for (int i = 0; i < 16; ++i)
      c[i] = fminf(b[i], lists[((w + 4) * 64 + lane) * 17 + (15 - i)]);
#pragma unroll
    for (int dd = 8; dd >= 1; dd >>= 1) {
#pragma unroll
      for (int i = 0; i < 16; ++i) {
        if ((i & dd) == 0) {
          float lo = fminf(c[i], c[i | dd]);
          float hi = fmaxf(c[i], c[i | dd]);
          c[i] = lo; c[i | dd] = hi;
        }
      }
    }
#pragma unroll
    for (int k = 0; k < 16; ++k) lists[(w * 64 + lane) * 17 + k] = c[k];
  }
  __syncthreads();
  // level 2: w<2 merges (w, w+2) -> sorted c -> lists[w]
  if (w < 2) {
#pragma unroll
    for (int i = 0; i < 16; ++i) {
      float o = lists[((w + 2) * 64 + lane) * 17 + (15 - i)];
      c[i] = fminf(c[i], o);
    }
#pragma unroll
    for (int dd = 8; dd >= 1; dd >>= 1) {
#pragma unroll
      for (int i = 0; i < 16; ++i) {
        if ((i & dd) == 0) {
          float lo = fminf(c[i], c[i | dd]);
          float hi = fmaxf(c[i], c[i | dd]);
          c[i] = lo; c[i | dd] = hi;
        }
      }
    }
#pragma unroll
    for (int k = 0; k < 16; ++k) lists[(w * 64 + lane) * 17 + k] = c[k];
  }
  __syncthreads();
  // level 3: w==0, set-only (order-free for aggregation)
  if (w == 0) {
#pragma unroll
    for (int i = 0; i < 16; ++i) {
      float o = lists[(64 + lane) * 17 + (15 - i)];
      fk[lane * 17 + i] = fminf(c[i], o);
    }
  }
  __syncthreads();

  // aggregation: wave w handles block-local nodes [w*8, w*8+8)
  const int q  = lane & 7;    // feature quad (8 bf16 = 1 uint4)
  const int nb = lane >> 3;   // neighbor slot (0..7; also slot+8)
  const u16* __restrict__ hg = h_buf + (size_t)g * L * FLR;

#pragma unroll 2
  for (int tt = 0; tt < 8; ++tt) {
    const int nodeL = w * 8 + tt;
    float k1 = fk[nodeL * 17 + nb];
    float k2 = fk[nodeL * 17 + 8 + nb];
    u32 u1 = __float_as_uint(k1), u2 = __float_as_uint(k2);
    float w1 = __expf(-10.0f * __uint_as_float(u1 & 0xFFFFFC00u));
    float w2 = __expf(-10.0f * __uint_as_float(u2 & 0xFFFFFC00u));
    const uint4 a  = ((const uint4*)(hg + (size_t)(u1 & 1023u) * FLR))[q];
    const uint4 b4 = ((const uint4*)(hg + (size_t)(u2 & 1023u) * FLR))[q];
    u32 pa[4] = {a.x, a.y, a.z, a.w};
    u32 pb[4] = {b4.x, b4.y, b4.z, b4.w};
    float m[8], xx[8];
#pragma unroll
    for (int d = 0; d < 4; ++d) {
      float a0 = __uint_as_float(pa[d] << 16) * w1;
      float a1 = __uint_as_float(pa[d] & 0xFFFF0000u) * w1;
      float b0 = __uint_as_float(pb[d] << 16) * w2;
      float b1 = __uint_as_float(pb[d] & 0xFFFF0000u) * w2;
      m[2 * d]     = a0 + b0;  xx[2 * d]     = fmaxf(a0, b0);
      m[2 * d + 1] = a1 + b1;  xx[2 * d + 1] = fmaxf(a1, b1);
    }
#pragma unroll
    for (int mask = 8; mask <= 32; mask <<= 1) {
#pragma unroll
      for (int jj = 0; jj < 8; ++jj) m[jj] += __shfl_xor(m[jj], mask, 64);
#pragma unroll
      for (int jj = 0; jj < 8; ++jj) xx[jj] = fmaxf(xx[jj], __shfl_xor(xx[jj], mask, 64));
    }
    u16* fr = agg + (size_t)(g * L + nb0 + nodeL) * 128;
    if (nb == 0) {
      uint4 o;
      o.x = pack2(m[0] * 0.0625f, m[1] * 0.0625f);
      o.y = pack2(m[2] * 0.0625f, m[3] * 0.0625f);
      o.z = pack2(m[4] * 0.0625f, m[5] * 0.0625f);
      o.w = pack2(m[6] * 0.0625f, m[7] * 0.0625f);
      *(uint4*)(fr + q * 8) = o;
    } else if (nb == 1) {
      uint4 o;
      o.x = pack2(xx[0], xx[1]); o.y = pack2(xx[2], xx[3]);
      o.z = pack2(xx[4], xx[5]); o.w = pack2(xx[6], xx[7]);
      *(uint4*)(fr + FLR + q * 8) = o;
    }
  }
}

// ---------------------------------------------------------------------------
// k_pack: repack fp32 W_out[256][128] into bf16 MFMA B-fragment order.
// ---------------------------------------------------------------------------
__global__ void k_pack(const float* __restrict__ Wout, u16* __restrict__ Bp)
{
  int t = blockIdx.x * 256 + threadIdx.x;    // 8 ntile * 8 kstep * 64 lane
  if (t >= 8 * 8 * 64) return;
  int lane = t & 63, kstep = (t >> 6) & 7, ntile = t >> 9;
  int n  = ntile * 16 + (lane & 15);
  int kb = kstep * 32 + (lane >> 4) * 8;
  u16* dst = Bp + (size_t)t * 8;
#pragma unroll
  for (int j = 0; j < 8; ++j) dst[j] = f2bf(Wout[(kb + j) * OUT + n]);
}

// ---------------------------------------------------------------------------
// k_out: out = relu([bf16(x) | agg] @ W_out + b_out), MFMA 16x16x32 bf16.
// A-frags ks<4 packed from fp32 x in-register (v_cvt_pk_bf16_f32);
// ks>=4 read from agg (bf16, row stride 128).
// A-frag: m=lane&15, k=(lane>>4)*8+j.  C/D: col=lane&15, row=(lane>>4)*4+reg.
// ---------------------------------------------------------------------------
__global__ __launch_bounds__(256) void k_out(
    const float* __restrict__ x, const u16* __restrict__ agg,
    const u16* __restrict__ Bp, const float* __restrict__ bout,
    float* __restrict__ out)
{
  const int wave = threadIdx.x >> 6;
  const int lane = threadIdx.x & 63;
  const int mbase = blockIdx.x * 64 + wave * 16;
  const int arow = mbase + (lane & 15);
  const int kq = (lane >> 4) * 8;

  f32x4 acc[8];
#pragma unroll
  for (int nt = 0; nt < 8; ++nt) acc[nt] = f32x4{0.f, 0.f, 0.f, 0.f};

  const float* xr = x + (size_t)arow * IN;
  const u16* ar = agg + (size_t)arow * 128;
  const bf16x8* __restrict__ bp = (const bf16x8*)Bp;

#pragma unroll
  for (int ks = 0; ks < 8; ++ks) {
    bf16x8 a;
    if (ks < 4) {
      float4 xa = *(const float4*)(xr + ks * 32 + kq);
      float4 xb = *(const float4*)(xr + ks * 32 + kq + 4);
      union { __hip_bfloat162 h2[4]; bf16x8 v; } cv;
      cv.h2[0] = __float22bfloat162_rn(float2{xa.x, xa.y});
      cv.h2[1] = __float22bfloat162_rn(float2{xa.z, xa.w});
      cv.h2[2] = __float22bfloat162_rn(float2{xb.x, xb.y});
      cv.h2[3] = __float22bfloat162_rn(float2{xb.z, xb.w});
      a = cv.v;
    } else {
      a = *(const bf16x8*)(ar + (ks - 4) * 32 + kq);
    }
#pragma unroll
    for (int nt = 0; nt < 8; ++nt) {
      bf16x8 b = bp[(nt * 8 + ks) * 64 + lane];
      acc[nt] = __builtin_amdgcn_mfma_f32_16x16x32_bf16(a, b, acc[nt], 0, 0, 0);
    }
  }

  const int rbase = (lane >> 4) * 4;
  const int col = lane & 15;
#pragma unroll
  for (int nt = 0; nt < 8; ++nt) {
    float bias = bout[nt * 16 + col];
#pragma unroll
    for (int r = 0; r < 4; ++r) {
      float v = acc[nt][r] + bias;
      out[(size_t)(mbase + rbase + r) * OUT + nt * 16 + col] = fmaxf(v, 0.0f);
    }
  }
}

extern "C" void kernel_launch(void* const* d_in, const int* in_sizes, int n_in,
                              void* d_out, int out_size, void* d_ws, size_t ws_size,
                              hipStream_t stream) {
  const float* x    = (const float*)d_in[0];
  const float* Ws   = (const float*)d_in[1];
  const float* bs   = (const float*)d_in[2];
  const float* Wh   = (const float*)d_in[3];
  const float* bh   = (const float*)d_in[4];
  const float* Wout = (const float*)d_in[5];
  const float* bout = (const float*)d_in[6];
  float* out = (float*)d_out;

  char* ws = (char*)d_ws;
  float* s_buf = (float*)ws;                                     // 1 MiB
  u16*   h_buf = (u16*)(ws + (1 << 20));                         // 8 MiB
  u16*   Bp    = (u16*)(ws + (1 << 20) + (8 << 20));             // 128 KiB
  u16*   agg   = (u16*)(ws + (1 << 20) + (8 << 20) + (1 << 17)); // 16 MiB

  k_sh<<<N / 64, 256, 0, stream>>>(x, Ws, bs, Wh, bh, s_buf, h_buf);
  k_pack<<<16, 256, 0, stream>>>(Wout, Bp);
  dim3 gknn(L / 64, Bb);
  k_knn<<<gknn, 512, 0, stream>>>(s_buf, h_buf, agg);
  k_out<<<N / 64, 256, 0, stream>>>(x, agg, Bp, bout, out);
}

// Round 6
// 187.904 us; speedup vs baseline: 3.2897x; 1.0587x over previous
//
#include <hip/hip_runtime.h>
#include <hip/hip_bf16.h>

using u16 = unsigned short;
using u32 = unsigned int;

typedef __bf16 bf16x8 __attribute__((ext_vector_type(8)));
typedef float f32x4 __attribute__((ext_vector_type(4)));

__device__ __forceinline__ u16 f2bf(float f) {
  union { float f; u32 u; } c; c.f = f;
  u32 u = c.u;
  u32 r = u + 0x7fffu + ((u >> 16) & 1u);   // RNE
  return (u16)(r >> 16);
}
__device__ __forceinline__ u32 pack2(float a, float b) {
  return (u32)f2bf(a) | ((u32)f2bf(b) << 16);
}

constexpr int Bb  = 64;    // graphs
constexpr int L   = 1024;  // nodes/graph
constexpr int IN  = 128;
constexpr int OUT = 128;
constexpr int FLR = 64;
constexpr int N   = Bb * L;

// ---------------------------------------------------------------------------
// k_sh: blocks 0..1023: 64 nodes each. Phase 1: coalesced fp32 x tile -> LDS.
// Phase 2: wave w computes h cols [w*16,w*16+16) (weights wave-uniform ->
// s_load) and s column w (fp32 exact). Block 1024: packs W_out into bf16
// MFMA B-fragment order (folded k_pack, saves a launch).
// ---------------------------------------------------------------------------
__global__ __launch_bounds__(256) void k_sh(
    const float* __restrict__ x, const float* __restrict__ Ws, const float* __restrict__ bs,
    const float* __restrict__ Wh, const float* __restrict__ bh,
    const float* __restrict__ Wout,
    float* __restrict__ s_buf, u16* __restrict__ h_buf, u16* __restrict__ Bp)
{
  const int blk = blockIdx.x;
  if (blk >= N / 64) {
    // ---- W_out pack: Bp[((ntile*8+kstep)*64+lane)*8+j] =
    //      bf16(Wout[(kstep*32+(lane>>4)*8+j)*128 + ntile*16+(lane&15)])
#pragma unroll
    for (int it = 0; it < 16; ++it) {
      int t2 = it * 256 + threadIdx.x;     // 4096 frag-lanes
      int lane = t2 & 63, kstep = (t2 >> 6) & 7, ntile = t2 >> 9;
      int n  = ntile * 16 + (lane & 15);
      int kb = kstep * 32 + (lane >> 4) * 8;
      u16* dst = Bp + (size_t)t2 * 8;
#pragma unroll
      for (int j = 0; j < 8; ++j) dst[j] = f2bf(Wout[(kb + j) * OUT + n]);
    }
    return;
  }

  __shared__ float xs[64 * 132];
  const int t = threadIdx.x;
  const float* xb = x + (size_t)blk * 64 * IN;

#pragma unroll
  for (int i = 0; i < 8; ++i) {
    int flat = i * 1024 + t * 4;
    float4 v = *(const float4*)(xb + flat);
    int node = flat >> 7, feat = flat & 127;
    *(float4*)(&xs[node * 132 + feat]) = v;
  }
  __syncthreads();

  const int lane = t & 63;
  const int w = __builtin_amdgcn_readfirstlane(t >> 6);
  const int node = blk * 64 + lane;
  const int ob = w * 16;

  float h[16];
#pragma unroll
  for (int o = 0; o < 16; ++o) h[o] = bh[ob + o];
  float sacc = bs[w];

  for (int f = 0; f < IN; f += 4) {
    float4 xc = *(const float4*)(&xs[lane * 132 + f]);
    float xv[4] = {xc.x, xc.y, xc.z, xc.w};
#pragma unroll
    for (int tt = 0; tt < 4; ++tt) {
      const float* wr = Wh + (size_t)(f + tt) * FLR + ob;
#pragma unroll
      for (int o = 0; o < 16; ++o) h[o] = fmaf(xv[tt], wr[o], h[o]);
      sacc = fmaf(xv[tt], Ws[(f + tt) * 4 + w], sacc);
    }
  }

  u16* hr = h_buf + (size_t)node * FLR + ob;
  uint4 p;
  p.x = pack2(h[0], h[1]);  p.y = pack2(h[2], h[3]);
  p.z = pack2(h[4], h[5]);  p.w = pack2(h[6], h[7]);
  *(uint4*)(hr) = p;
  p.x = pack2(h[8], h[9]);  p.y = pack2(h[10], h[11]);
  p.z = pack2(h[12], h[13]); p.w = pack2(h[14], h[15]);
  *(uint4*)(hr + 8) = p;

  s_buf[(size_t)node * 4 + w] = sacc;
}

// ---------------------------------------------------------------------------
// k_fused: knn select + aggregate (into LDS) + output GEMM, one block per
// 64 nodes of one graph (512 threads = 8 waves).
//   scan:  wave w scans candidates [w*128,(w+1)*128), med3 sorted-insert on
//          keys (bits(d2)&~1023)|j  (ties -> lower j, matches lax.top_k).
//   merge: 3-level bitonic min-identity tree (final level set-only) -> fk.
//   agg:   lane=(nb,q); one uint4 covers 8 neighbor rows x 8 quads; mean/max
//          via 3 shfl_xor steps; result -> LDS (aliased over dead lists[]).
//   gemm:  wave w = m-tile (w&3) x nt-half (w>>2); A ks<4 from fp32 x
//          (cvt in-register), ks>=4 from LDS agg; B from Bp; bias+ReLU store.
// ---------------------------------------------------------------------------
__global__ __launch_bounds__(512) void k_fused(
    const float* __restrict__ s_buf, const u16* __restrict__ h_buf,
    const float* __restrict__ x, const u16* __restrict__ Bp,
    const float* __restrict__ bout, float* __restrict__ out)
{
  __shared__ alignas(16) float lists[8 * 64 * 17];   // 34.8 KB; later aliased as agg
  __shared__ float fk[64 * 17];                      // final 16 keys per node
  u16* agg_lds = (u16*)lists;                        // [64][136] bf16, stride 136

  const int lane = threadIdx.x & 63;
  const int w = __builtin_amdgcn_readfirstlane(threadIdx.x >> 6);
  const int g = blockIdx.y;
  const int nb0 = blockIdx.x * 64;
  const int node = g * L + nb0 + lane;

  const float4 si = *(const float4*)(s_buf + (size_t)node * 4);
  const float4* __restrict__ sg = (const float4*)(s_buf + (size_t)g * L * 4);
  const int jb = __builtin_amdgcn_readfirstlane(w * 128);

  float b[16];
#pragma unroll
  for (int k = 0; k < 16; ++k) b[k] = 3.0e38f;

#pragma unroll 4
  for (int j = 0; j < 128; ++j) {
    float4 sj = sg[jb + j];
    float dx = si.x - sj.x, dy = si.y - sj.y;
    float dz = si.z - sj.z, dw2 = si.w - sj.w;
    float d2 = fmaf(dw2, dw2, fmaf(dz, dz, fmaf(dy, dy, dx * dx)));
    u32 db = __float_as_uint(d2);
    float key = __uint_as_float((db & 0xFFFFFC00u) | (u32)(jb + j));
#pragma unroll
    for (int k = 15; k >= 1; --k) b[k] = __builtin_amdgcn_fmed3f(key, b[k - 1], b[k]);
    b[0] = fminf(key, b[0]);
  }

#pragma unroll
  for (int k = 0; k < 16; ++k) lists[(w * 64 + lane) * 17 + k] = b[k];
  __syncthreads();

  float c[16];
  // level 1: w<4 merges (w, w+4)
  if (w < 4) {
#pragma unroll
    for (int i = 0; i < 16; ++i)
      c[i] = fminf(b[i], lists[((w + 4) * 64 + lane) * 17 + (15 - i)]);
#pragma unroll
    for (int dd = 8; dd >= 1; dd >>= 1) {
#pragma unroll
      for (int i = 0; i < 16; ++i) {
        if ((i & dd) == 0) {
          float lo = fminf(c[i], c[i | dd]);
          float hi = fmaxf(c[i], c[i | dd]);
          c[i] = lo; c[i | dd] = hi;
        }
      }
    }
#pragma unroll
    for (int k = 0; k < 16; ++k) lists[(w * 64 + lane) * 17 + k] = c[k];
  }
  __syncthreads();
  // level 2: w<2 merges (w, w+2)
  if (w < 2) {
#pragma unroll
    for (int i = 0; i < 16; ++i)
      c[i] = fminf(c[i], lists[((w + 2) * 64 + lane) * 17 + (15 - i)]);
#pragma unroll
    for (int dd = 8; dd >= 1; dd >>= 1) {
#pragma unroll
      for (int i = 0; i < 16; ++i) {
        if ((i & dd) == 0) {
          float lo = fminf(c[i], c[i | dd]);
          float hi = fmaxf(c[i], c[i | dd]);
          c[i] = lo; c[i | dd] = hi;
        }
      }
    }
#pragma unroll
    for (int k = 0; k < 16; ++k) lists[(w * 64 + lane) * 17 + k] = c[k];
  }
  __syncthreads();
  // level 3: w==0, set-only (order-free downstream)
  if (w == 0) {
#pragma unroll
    for (int i = 0; i < 16; ++i) {
      float o = lists[(64 + lane) * 17 + (15 - i)];
      fk[lane * 17 + i] = fminf(c[i], o);
    }
  }
  __syncthreads();        // fk ready; lists[] now dead -> reuse as agg_lds

  // ---- aggregation: wave w handles block-local nodes [w*8, w*8+8)
  const int q  = lane & 7;    // feature quad (8 bf16 = 1 uint4)
  const int nb = lane >> 3;   // neighbor slot (0..7; also slot+8)
  const u16* __restrict__ hg = h_buf + (size_t)g * L * FLR;

#pragma unroll 2
  for (int tt = 0; tt < 8; ++tt) {
    const int nodeL = w * 8 + tt;
    float k1 = fk[nodeL * 17 + nb];
    float k2 = fk[nodeL * 17 + 8 + nb];
    u32 u1 = __float_as_uint(k1), u2 = __float_as_uint(k2);
    float w1 = __expf(-10.0f * __uint_as_float(u1 & 0xFFFFFC00u));
    float w2 = __expf(-10.0f * __uint_as_float(u2 & 0xFFFFFC00u));
    const uint4 a  = ((const uint4*)(hg + (size_t)(u1 & 1023u) * FLR))[q];
    const uint4 b4 = ((const uint4*)(hg + (size_t)(u2 & 1023u) * FLR))[q];
    u32 pa[4] = {a.x, a.y, a.z, a.w};
    u32 pb[4] = {b4.x, b4.y, b4.z, b4.w};
    float m[8], xx[8];
#pragma unroll
    for (int d = 0; d < 4; ++d) {
      float a0 = __uint_as_float(pa[d] << 16) * w1;
      float a1 = __uint_as_float(pa[d] & 0xFFFF0000u) * w1;
      float b0 = __uint_as_float(pb[d] << 16) * w2;
      float b1 = __uint_as_float(pb[d] & 0xFFFF0000u) * w2;
      m[2 * d]     = a0 + b0;  xx[2 * d]     = fmaxf(a0, b0);
      m[2 * d + 1] = a1 + b1;  xx[2 * d + 1] = fmaxf(a1, b1);
    }
#pragma unroll
    for (int mask = 8; mask <= 32; mask <<= 1) {
#pragma unroll
      for (int jj = 0; jj < 8; ++jj) m[jj] += __shfl_xor(m[jj], mask, 64);
#pragma unroll
      for (int jj = 0; jj < 8; ++jj) xx[jj] = fmaxf(xx[jj], __shfl_xor(xx[jj], mask, 64));
    }
    if (nb == 0) {
      uint4 o;
      o.x = pack2(m[0] * 0.0625f, m[1] * 0.0625f);
      o.y = pack2(m[2] * 0.0625f, m[3] * 0.0625f);
      o.z = pack2(m[4] * 0.0625f, m[5] * 0.0625f);
      o.w = pack2(m[6] * 0.0625f, m[7] * 0.0625f);
      *(uint4*)(&agg_lds[nodeL * 136 + q * 8]) = o;
    } else if (nb == 1) {
      uint4 o;
      o.x = pack2(xx[0], xx[1]); o.y = pack2(xx[2], xx[3]);
      o.z = pack2(xx[4], xx[5]); o.w = pack2(xx[6], xx[7]);
      *(uint4*)(&agg_lds[nodeL * 136 + FLR + q * 8]) = o;
    }
  }
  __syncthreads();

  // ---- output GEMM: wave w = m-tile (w&3, 16 rows) x nt-half (w>>2)
  const int mt  = w & 3;
  const int ntb = (w >> 2) * 4;
  const int rowL = mt * 16 + (lane & 15);            // block-local row
  const int grow = g * L + nb0 + rowL;               // global node row
  const int kq = (lane >> 4) * 8;

  f32x4 acc[4];
#pragma unroll
  for (int nt = 0; nt < 4; ++nt) acc[nt] = f32x4{0.f, 0.f, 0.f, 0.f};

  const float* xr = x + (size_t)grow * IN;
  const bf16x8* __restrict__ bp = (const bf16x8*)Bp;

#pragma unroll
  for (int ks = 0; ks < 8; ++ks) {
    bf16x8 a;
    if (ks < 4) {
      float4 xa = *(const float4*)(xr + ks * 32 + kq);
      float4 xb = *(const float4*)(xr + ks * 32 + kq + 4);
      union { __hip_bfloat162 h2[4]; bf16x8 v; } cv;
      cv.h2[0] = __float22bfloat162_rn(float2{xa.x, xa.y});
      cv.h2[1] = __float22bfloat162_rn(float2{xa.z, xa.w});
      cv.h2[2] = __float22bfloat162_rn(float2{xb.x, xb.y});
      cv.h2[3] = __float22bfloat162_rn(float2{xb.z, xb.w});
      a = cv.v;
    } else {
      a = *(const bf16x8*)(&agg_lds[rowL * 136 + (ks - 4) * 32 + kq]);
    }
#pragma unroll
    for (int nt = 0; nt < 4; ++nt) {
      bf16x8 bb = bp[((ntb + nt) * 8 + ks) * 64 + lane];
      acc[nt] = __builtin_amdgcn_mfma_f32_16x16x32_bf16(a, bb, acc[nt], 0, 0, 0);
    }
  }

  const int rbase = (lane >> 4) * 4;
  const int col = lane & 15;
  const int mrow = g * L + nb0 + mt * 16;
#pragma unroll
  for (int nt = 0; nt < 4; ++nt) {
    float bias = bout[(ntb + nt) * 16 + col];
#pragma unroll
    for (int r = 0; r < 4; ++r) {
      float v = acc[nt][r] + bias;
      out[(size_t)(mrow + rbase + r) * OUT + (ntb + nt) * 16 + col] = fmaxf(v, 0.0f);
    }
  }
}

extern "C" void kernel_launch(void* const* d_in, const int* in_sizes, int n_in,
                              void* d_out, int out_size, void* d_ws, size_t ws_size,
                              hipStream_t stream) {
  const float* x    = (const float*)d_in[0];
  const float* Ws   = (const float*)d_in[1];
  const float* bs   = (const float*)d_in[2];
  const float* Wh   = (const float*)d_in[3];
  const float* bh   = (const float*)d_in[4];
  const float* Wout = (const float*)d_in[5];
  const float* bout = (const float*)d_in[6];
  float* out = (float*)d_out;

  char* ws = (char*)d_ws;
  float* s_buf = (float*)ws;                                     // 1 MiB
  u16*   h_buf = (u16*)(ws + (1 << 20));                         // 8 MiB
  u16*   Bp    = (u16*)(ws + (1 << 20) + (8 << 20));             // 64 KiB

  k_sh<<<N / 64 + 1, 256, 0, stream>>>(x, Ws, bs, Wh, bh, Wout, s_buf, h_buf, Bp);
  dim3 gknn(L / 64, Bb);
  k_fused<<<gknn, 512, 0, stream>>>(s_buf, h_buf, x, Bp, bout, out);
}

// Round 7
// 176.335 us; speedup vs baseline: 3.5055x; 1.0656x over previous
//
#include <hip/hip_runtime.h>
#include <hip/hip_bf16.h>

using u16 = unsigned short;
using u32 = unsigned int;

typedef __bf16 bf16x8 __attribute__((ext_vector_type(8)));
typedef float f32x4 __attribute__((ext_vector_type(4)));

__device__ __forceinline__ u16 f2bf(float f) {
  union { float f; u32 u; } c; c.f = f;
  u32 u = c.u;
  u32 r = u + 0x7fffu + ((u >> 16) & 1u);   // RNE
  return (u16)(r >> 16);
}
__device__ __forceinline__ u32 pack2(float a, float b) {
  return (u32)f2bf(a) | ((u32)f2bf(b) << 16);
}

constexpr int Bb  = 64;    // graphs
constexpr int L   = 1024;  // nodes/graph
constexpr int IN  = 128;
constexpr int OUT = 128;
constexpr int FLR = 64;
constexpr int N   = Bb * L;

// ---------------------------------------------------------------------------
// k_sh (MFMA version): blocks 0..1023 handle 64 nodes each; wave w = m-tile
// of 16 nodes. h = x@Wh+bh via 16 MFMAs/wave (A from fp32 x converted
// in-register, B from Wh global with on-the-fly bf16 conversion — Wh is
// 32 KB, L1/L2-hot). s = x@Ws+bs in fp32: each lane accumulates its A-frag's
// 32 k-values, butterfly shfl_xor(16,32) reduce across the 4 kq groups.
// Block 1024: packs W_out into MFMA B-frag order for k_fused.
// ---------------------------------------------------------------------------
__global__ __launch_bounds__(256) void k_sh(
    const float* __restrict__ x, const float* __restrict__ Ws, const float* __restrict__ bs,
    const float* __restrict__ Wh, const float* __restrict__ bh,
    const float* __restrict__ Wout,
    float* __restrict__ s_buf, u16* __restrict__ h_buf, u16* __restrict__ Bp)
{
  const int blk = blockIdx.x;
  if (blk >= N / 64) {
    // ---- W_out pack for k_fused's GEMM
#pragma unroll
    for (int it = 0; it < 16; ++it) {
      int t2 = it * 256 + threadIdx.x;     // 4096 frag-lanes
      int lane = t2 & 63, kstep = (t2 >> 6) & 7, ntile = t2 >> 9;
      int n  = ntile * 16 + (lane & 15);
      int kb = kstep * 32 + (lane >> 4) * 8;
      u16* dst = Bp + (size_t)t2 * 8;
#pragma unroll
      for (int j = 0; j < 8; ++j) dst[j] = f2bf(Wout[(kb + j) * OUT + n]);
    }
    return;
  }

  const int lane = threadIdx.x & 63;
  const int w = __builtin_amdgcn_readfirstlane(threadIdx.x >> 6);
  const int mb = blk * 64 + w * 16;        // m-tile base node
  const int col = lane & 15;
  const int kq  = lane >> 4;               // 0..3
  const int mrow = mb + col;               // this lane's A row

  const float* xr = x + (size_t)mrow * IN;

  // ---- load x A-frags (fp32->bf16) + accumulate s partials in fp32
  float sp0 = 0.f, sp1 = 0.f, sp2 = 0.f, sp3 = 0.f;
  bf16x8 a[4];
#pragma unroll
  for (int ks = 0; ks < 4; ++ks) {
    float4 xa = *(const float4*)(xr + ks * 32 + kq * 8);
    float4 xb = *(const float4*)(xr + ks * 32 + kq * 8 + 4);
    float xf[8] = {xa.x, xa.y, xa.z, xa.w, xb.x, xb.y, xb.z, xb.w};
#pragma unroll
    for (int j = 0; j < 8; ++j) {
      const float4 wsr = *(const float4*)(Ws + (size_t)(ks * 32 + kq * 8 + j) * 4);
      sp0 = fmaf(xf[j], wsr.x, sp0);
      sp1 = fmaf(xf[j], wsr.y, sp1);
      sp2 = fmaf(xf[j], wsr.z, sp2);
      sp3 = fmaf(xf[j], wsr.w, sp3);
    }
    union { __hip_bfloat162 h2[4]; bf16x8 v; } cv;
    cv.h2[0] = __float22bfloat162_rn(float2{xf[0], xf[1]});
    cv.h2[1] = __float22bfloat162_rn(float2{xf[2], xf[3]});
    cv.h2[2] = __float22bfloat162_rn(float2{xf[4], xf[5]});
    cv.h2[3] = __float22bfloat162_rn(float2{xf[6], xf[7]});
    a[ks] = cv.v;
  }

  // ---- h GEMM: 4 n-tiles x 4 k-steps; B-frag from Wh on the fly
  f32x4 acc[4];
#pragma unroll
  for (int nt = 0; nt < 4; ++nt) acc[nt] = f32x4{0.f, 0.f, 0.f, 0.f};

#pragma unroll
  for (int nt = 0; nt < 4; ++nt) {
#pragma unroll
    for (int ks = 0; ks < 4; ++ks) {
      const float* whb = Wh + (size_t)(ks * 32 + kq * 8) * FLR + nt * 16 + col;
      union { __hip_bfloat162 h2[4]; bf16x8 v; } bv;
#pragma unroll
      for (int j = 0; j < 4; ++j)
        bv.h2[j] = __float22bfloat162_rn(float2{whb[(2 * j) * FLR], whb[(2 * j + 1) * FLR]});
      acc[nt] = __builtin_amdgcn_mfma_f32_16x16x32_bf16(a[ks], bv.v, acc[nt], 0, 0, 0);
    }
  }

  // ---- s reduce + store (fp32)
  sp0 += __shfl_xor(sp0, 16, 64); sp0 += __shfl_xor(sp0, 32, 64);
  sp1 += __shfl_xor(sp1, 16, 64); sp1 += __shfl_xor(sp1, 32, 64);
  sp2 += __shfl_xor(sp2, 16, 64); sp2 += __shfl_xor(sp2, 32, 64);
  sp3 += __shfl_xor(sp3, 16, 64); sp3 += __shfl_xor(sp3, 32, 64);
  if (kq == 0) {
    float4 sv;
    sv.x = sp0 + bs[0]; sv.y = sp1 + bs[1];
    sv.z = sp2 + bs[2]; sv.w = sp3 + bs[3];
    *(float4*)(s_buf + (size_t)mrow * 4) = sv;
  }

  // ---- h epilogue: bias + bf16 store (C-layout: col=lane&15, row=kq*4+r)
#pragma unroll
  for (int nt = 0; nt < 4; ++nt) {
    float bias = bh[nt * 16 + col];
#pragma unroll
    for (int r = 0; r < 4; ++r) {
      float v = acc[nt][r] + bias;
      h_buf[(size_t)(mb + kq * 4 + r) * FLR + nt * 16 + col] = f2bf(v);
    }
  }
}

// ---------------------------------------------------------------------------
// k_fused: knn select + aggregate (into LDS) + output GEMM, one block per
// 64 nodes of one graph (512 threads = 8 waves). Unchanged from round 6.
// ---------------------------------------------------------------------------
__global__ __launch_bounds__(512) void k_fused(
    const float* __restrict__ s_buf, const u16* __restrict__ h_buf,
    const float* __restrict__ x, const u16* __restrict__ Bp,
    const float* __restrict__ bout, float* __restrict__ out)
{
  __shared__ alignas(16) float lists[8 * 64 * 17];   // 34.8 KB; later aliased as agg
  __shared__ float fk[64 * 17];                      // final 16 keys per node
  u16* agg_lds = (u16*)lists;                        // [64][136] bf16, stride 136

  const int lane = threadIdx.x & 63;
  const int w = __builtin_amdgcn_readfirstlane(threadIdx.x >> 6);
  const int g = blockIdx.y;
  const int nb0 = blockIdx.x * 64;
  const int node = g * L + nb0 + lane;

  const float4 si = *(const float4*)(s_buf + (size_t)node * 4);
  const float4* __restrict__ sg = (const float4*)(s_buf + (size_t)g * L * 4);
  const int jb = __builtin_amdgcn_readfirstlane(w * 128);

  float b[16];
#pragma unroll
  for (int k = 0; k < 16; ++k) b[k] = 3.0e38f;

#pragma unroll 4
  for (int j = 0; j < 128; ++j) {
    float4 sj = sg[jb + j];
    float dx = si.x - sj.x, dy = si.y - sj.y;
    float dz = si.z - sj.z, dw2 = si.w - sj.w;
    float d2 = fmaf(dw2, dw2, fmaf(dz, dz, fmaf(dy, dy, dx * dx)));
    u32 db = __float_as_uint(d2);
    float key = __uint_as_float((db & 0xFFFFFC00u) | (u32)(jb + j));
#pragma unroll
    for (int k = 15; k >= 1; --k) b[k] = __builtin_amdgcn_fmed3f(key, b[k - 1], b[k]);
    b[0] = fminf(key, b[0]);
  }

#pragma unroll
  for (int k = 0; k < 16; ++k) lists[(w * 64 + lane) * 17 + k] = b[k];
  __syncthreads();

  float c[16];
  if (w < 4) {
#pragma unroll
    for (int i = 0; i < 16; ++i)
      c[i] = fminf(b[i], lists[((w + 4) * 64 + lane) * 17 + (15 - i)]);
#pragma unroll
    for (int dd = 8; dd >= 1; dd >>= 1) {
#pragma unroll
      for (int i = 0; i < 16; ++i) {
        if ((i & dd) == 0) {
          float lo = fminf(c[i], c[i | dd]);
          float hi = fmaxf(c[i], c[i | dd]);
          c[i] = lo; c[i | dd] = hi;
        }
      }
    }
#pragma unroll
    for (int k = 0; k < 16; ++k) lists[(w * 64 + lane) * 17 + k] = c[k];
  }
  __syncthreads();
  if (w < 2) {
#pragma unroll
    for (int i = 0; i < 16; ++i)
      c[i] = fminf(c[i], lists[((w + 2) * 64 + lane) * 17 + (15 - i)]);
#pragma unroll
    for (int dd = 8; dd >= 1; dd >>= 1) {
#pragma unroll
      for (int i = 0; i < 16; ++i) {
        if ((i & dd) == 0) {
          float lo = fminf(c[i], c[i | dd]);
          float hi = fmaxf(c[i], c[i | dd]);
          c[i] = lo; c[i | dd] = hi;
        }
      }
    }
#pragma unroll
    for (int k = 0; k < 16; ++k) lists[(w * 64 + lane) * 17 + k] = c[k];
  }
  __syncthreads();
  if (w == 0) {
#pragma unroll
    for (int i = 0; i < 16; ++i) {
      float o = lists[(64 + lane) * 17 + (15 - i)];
      fk[lane * 17 + i] = fminf(c[i], o);
    }
  }
  __syncthreads();        // fk ready; lists[] now dead -> reuse as agg_lds

  const int q  = lane & 7;
  const int nb = lane >> 3;
  const u16* __restrict__ hg = h_buf + (size_t)g * L * FLR;

#pragma unroll 2
  for (int tt = 0; tt < 8; ++tt) {
    const int nodeL = w * 8 + tt;
    float k1 = fk[nodeL * 17 + nb];
    float k2 = fk[nodeL * 17 + 8 + nb];
    u32 u1 = __float_as_uint(k1), u2 = __float_as_uint(k2);
    float w1 = __expf(-10.0f * __uint_as_float(u1 & 0xFFFFFC00u));
    float w2 = __expf(-10.0f * __uint_as_float(u2 & 0xFFFFFC00u));
    const uint4 a  = ((const uint4*)(hg + (size_t)(u1 & 1023u) * FLR))[q];
    const uint4 b4 = ((const uint4*)(hg + (size_t)(u2 & 1023u) * FLR))[q];
    u32 pa[4] = {a.x, a.y, a.z, a.w};
    u32 pb[4] = {b4.x, b4.y, b4.z, b4.w};
    float m[8], xx[8];
#pragma unroll
    for (int d = 0; d < 4; ++d) {
      float a0 = __uint_as_float(pa[d] << 16) * w1;
      float a1 = __uint_as_float(pa[d] & 0xFFFF0000u) * w1;
      float b0 = __uint_as_float(pb[d] << 16) * w2;
      float b1 = __uint_as_float(pb[d] & 0xFFFF0000u) * w2;
      m[2 * d]     = a0 + b0;  xx[2 * d]     = fmaxf(a0, b0);
      m[2 * d + 1] = a1 + b1;  xx[2 * d + 1] = fmaxf(a1, b1);
    }
#pragma unroll
    for (int mask = 8; mask <= 32; mask <<= 1) {
#pragma unroll
      for (int jj = 0; jj < 8; ++jj) m[jj] += __shfl_xor(m[jj], mask, 64);
#pragma unroll
      for (int jj = 0; jj < 8; ++jj) xx[jj] = fmaxf(xx[jj], __shfl_xor(xx[jj], mask, 64));
    }
    if (nb == 0) {
      uint4 o;
      o.x = pack2(m[0] * 0.0625f, m[1] * 0.0625f);
      o.y = pack2(m[2] * 0.0625f, m[3] * 0.0625f);
      o.z = pack2(m[4] * 0.0625f, m[5] * 0.0625f);
      o.w = pack2(m[6] * 0.0625f, m[7] * 0.0625f);
      *(uint4*)(&agg_lds[nodeL * 136 + q * 8]) = o;
    } else if (nb == 1) {
      uint4 o;
      o.x = pack2(xx[0], xx[1]); o.y = pack2(xx[2], xx[3]);
      o.z = pack2(xx[4], xx[5]); o.w = pack2(xx[6], xx[7]);
      *(uint4*)(&agg_lds[nodeL * 136 + FLR + q * 8]) = o;
    }
  }
  __syncthreads();

  const int mt  = w & 3;
  const int ntb = (w >> 2) * 4;
  const int rowL = mt * 16 + (lane & 15);
  const int grow = g * L + nb0 + rowL;
  const int kq = (lane >> 4) * 8;

  f32x4 acc[4];
#pragma unroll
  for (int nt = 0; nt < 4; ++nt) acc[nt] = f32x4{0.f, 0.f, 0.f, 0.f};

  const float* xr = x + (size_t)grow * IN;
  const bf16x8* __restrict__ bp = (const bf16x8*)Bp;

#pragma unroll
  for (int ks = 0; ks < 8; ++ks) {
    bf16x8 a;
    if (ks < 4) {
      float4 xa = *(const float4*)(xr + ks * 32 + kq);
      float4 xb = *(const float4*)(xr + ks * 32 + kq + 4);
      union { __hip_bfloat162 h2[4]; bf16x8 v; } cv;
      cv.h2[0] = __float22bfloat162_rn(float2{xa.x, xa.y});
      cv.h2[1] = __float22bfloat162_rn(float2{xa.z, xa.w});
      cv.h2[2] = __float22bfloat162_rn(float2{xb.x, xb.y});
      cv.h2[3] = __float22bfloat162_rn(float2{xb.z, xb.w});
      a = cv.v;
    } else {
      a = *(const bf16x8*)(&agg_lds[rowL * 136 + (ks - 4) * 32 + kq]);
    }
#pragma unroll
    for (int nt = 0; nt < 4; ++nt) {
      bf16x8 bb = bp[((ntb + nt) * 8 + ks) * 64 + lane];
      acc[nt] = __builtin_amdgcn_mfma_f32_16x16x32_bf16(a, bb, acc[nt], 0, 0, 0);
    }
  }

  const int rbase = (lane >> 4) * 4;
  const int col = lane & 15;
  const int mrow = g * L + nb0 + mt * 16;
#pragma unroll
  for (int nt = 0; nt < 4; ++nt) {
    float bias = bout[(ntb + nt) * 16 + col];
#pragma unroll
    for (int r = 0; r < 4; ++r) {
      float v = acc[nt][r] + bias;
      out[(size_t)(mrow + rbase + r) * OUT + (ntb + nt) * 16 + col] = fmaxf(v, 0.0f);
    }
  }
}

extern "C" void kernel_launch(void* const* d_in, const int* in_sizes, int n_in,
                              void* d_out, int out_size, void* d_ws, size_t ws_size,
                              hipStream_t stream) {
  const float* x    = (const float*)d_in[0];
  const float* Ws   = (const float*)d_in[1];
  const float* bs   = (const float*)d_in[2];
  const float* Wh   = (const float*)d_in[3];
  const float* bh   = (const float*)d_in[4];
  const float* Wout = (const float*)d_in[5];
  const float* bout = (const float*)d_in[6];
  float* out = (float*)d_out;

  char* ws = (char*)d_ws;
  float* s_buf = (float*)ws;                                     // 1 MiB
  u16*   h_buf = (u16*)(ws + (1 << 20));                         // 8 MiB
  u16*   Bp    = (u16*)(ws + (1 << 20) + (8 << 20));             // 64 KiB

  k_sh<<<N / 64 + 1, 256, 0, stream>>>(x, Ws, bs, Wh, bh, Wout, s_buf, h_buf, Bp);
  dim3 gknn(L / 64, Bb);
  k_fused<<<gknn, 512, 0, stream>>>(s_buf, h_buf, x, Bp, bout, out);
}